// Round 2
// baseline (55.697 us; speedup 1.0000x reference)
//
#include <hip/hip_runtime.h>
#include <stdint.h>

typedef __attribute__((ext_vector_type(4))) float  f32x4;
typedef __attribute__((ext_vector_type(8))) __bf16 bf16x8;

#define NB   32
#define CC   512
#define DD   512
#define HW   1024
#define BM   128
#define BN   128
#define BK   32
#define NKS  (DD / BK)   // 16

static __device__ __forceinline__ uint32_t f2bf(float x) {
    uint32_t u = __float_as_uint(x);
    return (u + 0x7FFFu + ((u >> 16) & 1u)) >> 16;   // RNE bf16
}

// ---------------- softmax over last dim of atts -> bf16 W in ws -------------
// one wave per row (n,c); 512 cols; 8 floats per lane (two float4, coalesced)
__global__ __launch_bounds__(256) void softmax_rows(
        const float* __restrict__ atts, unsigned short* __restrict__ W) {
    const int tid  = threadIdx.x;
    const int wid  = tid >> 6;
    const int lane = tid & 63;
    const int row  = blockIdx.x * 4 + wid;          // 0..16383
    const float* a = atts + (size_t)row * DD;

    float4 v0 = *(const float4*)(a + lane * 4);
    float4 v1 = *(const float4*)(a + 256 + lane * 4);
    float e[8] = {v0.x, v0.y, v0.z, v0.w, v1.x, v1.y, v1.z, v1.w};

    float m = e[0];
    #pragma unroll
    for (int j = 1; j < 8; ++j) m = fmaxf(m, e[j]);
    #pragma unroll
    for (int s = 1; s < 64; s <<= 1) m = fmaxf(m, __shfl_xor(m, s, 64));

    float sum = 0.f;
    #pragma unroll
    for (int j = 0; j < 8; ++j) { e[j] = __expf(e[j] - m); sum += e[j]; }
    #pragma unroll
    for (int s = 1; s < 64; s <<= 1) sum += __shfl_xor(sum, s, 64);
    const float inv = 1.0f / sum;

    uint32_t p[4];
    #pragma unroll
    for (int j = 0; j < 4; ++j)
        p[j] = f2bf(e[2*j] * inv) | (f2bf(e[2*j+1] * inv) << 16);

    unsigned short* wr = W + (size_t)row * DD;
    uint2 s0 = {p[0], p[1]};
    uint2 s1 = {p[2], p[3]};
    *(uint2*)(wr + lane * 4)       = s0;            // 8B/lane, coalesced
    *(uint2*)(wr + 256 + lane * 4) = s1;
}

// ---------------- batched GEMM: out[n] = W[n] (512x512) x images[n] (512x1024)
// 128x128 tile, BK=32, 4 waves (2x2 of 64x64), mfma 16x16x32 bf16
// 2-phase double-buffered: stage(ks+1) issued before MFMA(ks), one barrier/ks
__global__ __launch_bounds__(256) void gemm_kernel(
        const float* __restrict__ images, const unsigned short* __restrict__ W,
        float* __restrict__ out) {
    __shared__ unsigned short lA[2][BM * BK];       // 2 x 8KB, [row][kg][8] linear
    __shared__ unsigned short lB[2][4 * BN * 8];    // 2 x 8KB, slot-swizzled [kg][n][8]

    // XCD-aware swizzle: all 32 tiles of batch n land on XCD n%8
    const int b  = blockIdx.x;       // 0..1023
    const int g  = b & 7;
    const int i  = b >> 3;           // 0..127
    const int n  = (i >> 5) * 8 + g; // batch 0..31
    const int tl = i & 31;
    const int mb = tl >> 3;          // 0..3
    const int nb = tl & 7;           // 0..7

    const float*          gI = images + (size_t)n * DD * HW + nb * BN;
    const unsigned short* gW = W + (size_t)n * CC * DD + (size_t)(mb * BM) * DD;
    float*                gO = out + (size_t)n * CC * HW + (size_t)(mb * BM) * HW + nb * BN;

    const int tid  = threadIdx.x;
    const int lane = tid & 63;
    const int wid  = tid >> 6;
    const int wm   = wid >> 1;       // 0..1
    const int wn   = wid & 1;        // 0..1
    const int bkg  = wid;            // B staging k-group = wave id (0..3)
    const int bn   = lane * 2;       // 0..126
    const int r15  = lane & 15;
    const int kgl  = lane >> 4;

    // swizzle flips: slot s -> s ^ ((s>>3)&1), 16B-granule XOR breaks the
    // 4-way ds_write quad conflict (write: bit3 of lane*2; read: bit3 of r15)
    const int wfl = (lane >> 2) & 1;
    const int rfl = (r15 >> 3) & 1;
    const int ws0 = (bkg * BN + bn) ^ wfl;
    const int ws1 = (bkg * BN + bn + 1) ^ wfl;

    f32x4 acc[4][4] = {};
    float xa[8], xb[8];

    auto stage_a = [&](int buf, int ks) {
        #pragma unroll
        for (int p = 0; p < 2; ++p) {
            const int idx = p * 256 + tid;
            const int row = idx >> 2;
            const int kg  = idx & 3;
            const unsigned short* src = gW + (size_t)row * DD + ks * BK + kg * 8;
            __builtin_amdgcn_global_load_lds(
                (const __attribute__((address_space(1))) void*)src,
                (__attribute__((address_space(3))) void*)&lA[buf][idx * 8],
                16, 0, 0);
        }
    };
    auto load_b = [&](int ks) {
        const float* srcB = gI + (size_t)(ks * BK + bkg * 8) * HW + bn;
        #pragma unroll
        for (int j = 0; j < 8; ++j) {
            float2 v = *(const float2*)(srcB + (size_t)j * HW);
            xa[j] = v.x; xb[j] = v.y;
        }
    };
    auto write_b = [&](int buf) {
        bf16x8 wa, wb;
        #pragma unroll
        for (int j = 0; j < 8; ++j) { wa[j] = (__bf16)xa[j]; wb[j] = (__bf16)xb[j]; }
        *(bf16x8*)&lB[buf][ws0 * 8] = wa;
        *(bf16x8*)&lB[buf][ws1 * 8] = wb;
    };
    auto compute = [&](int buf) {
        bf16x8 af[4], bv[4];
        #pragma unroll
        for (int m = 0; m < 4; ++m)
            af[m] = *(const bf16x8*)&lA[buf][(wm * 64 + m * 16 + r15) * BK + kgl * 8];
        #pragma unroll
        for (int nf = 0; nf < 4; ++nf) {
            const int s = (kgl * BN + wn * 64 + nf * 16 + r15) ^ rfl;
            bv[nf] = *(const bf16x8*)&lB[buf][s * 8];
        }
        #pragma unroll
        for (int m = 0; m < 4; ++m)
            #pragma unroll
            for (int nf = 0; nf < 4; ++nf)
                acc[m][nf] = __builtin_amdgcn_mfma_f32_16x16x32_bf16(
                    af[m], bv[nf], acc[m][nf], 0, 0, 0);
    };

    // prologue: fill buffer 0 with ks=0
    stage_a(0, 0);
    load_b(0);
    write_b(0);
    __syncthreads();

    int cur = 0;
    for (int ks = 0; ks < NKS; ++ks) {
        if (ks + 1 < NKS) {         // issue next tile's loads BEFORE compute
            stage_a(cur ^ 1, ks + 1);
            load_b(ks + 1);
        }
        compute(cur);
        if (ks + 1 < NKS)           // convert + LDS-write after compute
            write_b(cur ^ 1);
        __syncthreads();
        cur ^= 1;
    }

    // ---- epilogue: C/D layout col=lane&15, row=(lane>>4)*4+r ----
    #pragma unroll
    for (int m = 0; m < 4; ++m)
        #pragma unroll
        for (int nf = 0; nf < 4; ++nf)
            #pragma unroll
            for (int r = 0; r < 4; ++r) {
                const int row = wm * 64 + m * 16 + kgl * 4 + r;
                const int col = wn * 64 + nf * 16 + r15;
                gO[(size_t)row * HW + col] = acc[m][nf][r];
            }
}

extern "C" void kernel_launch(void* const* d_in, const int* in_sizes, int n_in,
                              void* d_out, int out_size, void* d_ws, size_t ws_size,
                              hipStream_t stream) {
    const float* images = (const float*)d_in[0];
    const float* atts   = (const float*)d_in[1];
    float*       out    = (float*)d_out;
    unsigned short* Wbf = (unsigned short*)d_ws;   // 32*512*512*2 = 16.8 MB

    softmax_rows<<<dim3(NB * CC / 4), dim3(256), 0, stream>>>(atts, Wbf);
    gemm_kernel<<<dim3(NB * (CC / BM) * (HW / BN)), dim3(256), 0, stream>>>(images, Wbf, out);
}

// Round 3
// 49.674 us; speedup vs baseline: 1.1213x; 1.1213x over previous
//
#include <hip/hip_runtime.h>
#include <stdint.h>

typedef __attribute__((ext_vector_type(4))) float  f32x4;
typedef __attribute__((ext_vector_type(8))) __bf16 bf16x8;

#define NB   32
#define CC   512
#define DD   512
#define HW   1024
#define BM   128
#define BN   128
#define BK   32
#define NKS  (DD / BK)   // 16

#define WAITV(N) asm volatile("s_waitcnt vmcnt(" #N ")" ::: "memory")
#define WAITL()  asm volatile("s_waitcnt lgkmcnt(0)" ::: "memory")
#define BAR()    do { asm volatile("" ::: "memory"); __builtin_amdgcn_s_barrier(); \
                      asm volatile("" ::: "memory"); } while (0)

static __device__ __forceinline__ uint32_t f2bf(float x) {
    uint32_t u = __float_as_uint(x);
    return (u + 0x7FFFu + ((u >> 16) & 1u)) >> 16;   // RNE bf16
}

// ---------------- softmax over last dim of atts -> bf16 W in ws -------------
__global__ __launch_bounds__(256) void softmax_rows(
        const float* __restrict__ atts, unsigned short* __restrict__ W) {
    const int tid  = threadIdx.x;
    const int wid  = tid >> 6;
    const int lane = tid & 63;
    const int row  = blockIdx.x * 4 + wid;          // 0..16383
    const float* a = atts + (size_t)row * DD;

    float4 v0 = *(const float4*)(a + lane * 4);
    float4 v1 = *(const float4*)(a + 256 + lane * 4);
    float e[8] = {v0.x, v0.y, v0.z, v0.w, v1.x, v1.y, v1.z, v1.w};

    float m = e[0];
    #pragma unroll
    for (int j = 1; j < 8; ++j) m = fmaxf(m, e[j]);
    #pragma unroll
    for (int s = 1; s < 64; s <<= 1) m = fmaxf(m, __shfl_xor(m, s, 64));

    float sum = 0.f;
    #pragma unroll
    for (int j = 0; j < 8; ++j) { e[j] = __expf(e[j] - m); sum += e[j]; }
    #pragma unroll
    for (int s = 1; s < 64; s <<= 1) sum += __shfl_xor(sum, s, 64);
    const float inv = 1.0f / sum;

    uint32_t p[4];
    #pragma unroll
    for (int j = 0; j < 4; ++j)
        p[j] = f2bf(e[2*j] * inv) | (f2bf(e[2*j+1] * inv) << 16);

    unsigned short* wr = W + (size_t)row * DD;
    uint2 s0 = {p[0], p[1]};
    uint2 s1 = {p[2], p[3]};
    *(uint2*)(wr + lane * 4)       = s0;
    *(uint2*)(wr + 256 + lane * 4) = s1;
}

// ---------------- batched GEMM: out[n] = W[n] (512x512) x images[n] (512x1024)
// counted-vmcnt pipeline: B loaded 2 steps ahead (2 reg sets), A via
// global_load_lds 1 step ahead; raw s_barrier, vmcnt never drained to 0
// in the main loop. Per-iter vmem = 8 (B float2) + 2 (A gload_lds x16B).
__global__ __launch_bounds__(256) void gemm_kernel(
        const float* __restrict__ images, const unsigned short* __restrict__ W,
        float* __restrict__ out) {
    __shared__ unsigned short lA[2][BM * BK];       // 2 x 8KB, src-preswizzled
    __shared__ unsigned short lB[2][4 * BN * 8];    // 2 x 8KB, slot-swizzled

    // XCD-aware swizzle: all 32 tiles of batch n land on XCD n%8
    const int b  = blockIdx.x;       // 0..1023
    const int g  = b & 7;
    const int i  = b >> 3;
    const int n  = (i >> 5) * 8 + g; // batch 0..31
    const int tl = i & 31;
    const int mb = tl >> 3;          // 0..3
    const int nb = tl & 7;           // 0..7

    const float*          gI = images + (size_t)n * DD * HW + nb * BN;
    const unsigned short* gW = W + (size_t)n * CC * DD + (size_t)(mb * BM) * DD;
    float*                gO = out + (size_t)n * CC * HW + (size_t)(mb * BM) * HW + nb * BN;

    const int tid  = threadIdx.x;
    const int lane = tid & 63;
    const int wid  = tid >> 6;
    const int wm   = wid >> 1;
    const int wn   = wid & 1;
    const int bkg  = wid;            // B staging k-group = wave id
    const int bn   = lane * 2;
    const int r15  = lane & 15;
    const int kgl  = lane >> 4;

    // lB slot swizzle: s ^= (s>>3)&1 (16B granule)
    const int wfl = (lane >> 2) & 1;
    const int rfl = (r15 >> 3) & 1;
    const int ws0 = (bkg * BN + bn) ^ wfl;
    const int ws1 = (bkg * BN + bn + 1) ^ wfl;
    // lA read sub-slot swizzle (source is pre-swizzled to match)
    const int ksw = (kgl ^ (r15 & 3)) * 8;

    f32x4 acc[4][4] = {};
    float2 ra[8], rb[8];             // two B register sets (2-step pipeline)

    auto stage_a = [&](int buf, int ks) {
        #pragma unroll
        for (int p = 0; p < 2; ++p) {
            const int idx = p * 256 + tid;
            const int row = idx >> 2;
            const int s   = idx & 3;
            const int ss  = s ^ (row & 3);          // inverse-swizzled source
            const unsigned short* src = gW + (size_t)row * DD + ks * BK + ss * 8;
            __builtin_amdgcn_global_load_lds(
                (const __attribute__((address_space(1))) void*)src,
                (__attribute__((address_space(3))) void*)&lA[buf][idx * 8],
                16, 0, 0);
        }
    };
    auto load_b = [&](int ks, float2 (&dst)[8]) {
        const float* srcB = gI + (size_t)(ks * BK + bkg * 8) * HW + bn;
        #pragma unroll
        for (int j = 0; j < 8; ++j)
            dst[j] = *(const float2*)(srcB + (size_t)j * HW);
    };
    auto write_b = [&](int buf, float2 (&us)[8]) {
        bf16x8 wa, wb;
        #pragma unroll
        for (int j = 0; j < 8; ++j) {
            wa[j] = (__bf16)us[j].x; wb[j] = (__bf16)us[j].y;
        }
        *(bf16x8*)&lB[buf][ws0 * 8] = wa;
        *(bf16x8*)&lB[buf][ws1 * 8] = wb;
    };
    auto compute = [&](int cur) {
        bf16x8 af[4], bv[4];
        #pragma unroll
        for (int m = 0; m < 4; ++m)
            af[m] = *(const bf16x8*)&lA[cur][(wm * 64 + m * 16 + r15) * BK + ksw];
        #pragma unroll
        for (int nf = 0; nf < 4; ++nf) {
            const int s = (kgl * BN + wn * 64 + nf * 16 + r15) ^ rfl;
            bv[nf] = *(const bf16x8*)&lB[cur][s * 8];
        }
        #pragma unroll
        for (int m = 0; m < 4; ++m)
            #pragma unroll
            for (int nf = 0; nf < 4; ++nf)
                acc[m][nf] = __builtin_amdgcn_mfma_f32_16x16x32_bf16(
                    af[m], bv[nf], acc[m][nf], 0, 0, 0);
    };

    // ---- prologue: B0->ra, A0->lA0, B1->rb; write lB0 ----
    load_b(0, ra);                   // 8 vmem  [B0]
    stage_a(0, 0);                   // 2       [B0 A0]
    load_b(1, rb);                   // 8       [B0 A0 B1]
    WAITV(10);                       // B0 done
    write_b(0, ra);
    WAITV(8);                        // A0 done  -> [B1]
    WAITL();
    BAR();

    // ---- iter 0 (special: A0 already drained) ----
    load_b(2, ra);                   // [B1 B2]
    stage_a(1, 1);                   // [B1 B2 A1]
    WAITV(10);                       // B1 done -> [B2 A1] = invariant
    write_b(1, rb);
    WAITL();
    BAR();
    compute(0);
    BAR();

    // ---- main loop ks = 1..13: invariant at top = [B(ks+1) x8, A(ks) x2] ----
    auto body = [&](int ks, float2 (&ld)[8], float2 (&us)[8]) {
        const int cur = ks & 1, nxt = cur ^ 1;
        load_b(ks + 2, ld);          // +8 -> 18
        stage_a(nxt, ks + 1);        // +2 -> 20
        WAITV(12);                   // B(ks+1) done
        write_b(nxt, us);
        WAITV(10);                   // A(ks) done -> [B(ks+2) A(ks+1)]
        WAITL();
        BAR();
        compute(cur);
        BAR();
    };
    #pragma unroll
    for (int ks = 1; ks <= 13; ++ks) {
        if (ks & 1) body(ks, rb, ra);   // odd: load rb, consume ra
        else        body(ks, ra, rb);   // even: load ra, consume rb
    }

    // ---- iter 14: top = [B15 x8, A14 x2]; no more B loads ----
    stage_a(1, 15);                  // [B15 A14 A15]
    WAITV(4);                        // B15 done
    write_b(1, rb);
    WAITV(0);                        // A14, A15 done (tail drain)
    WAITL();
    BAR();
    compute(0);
    BAR();

    // ---- iter 15: everything resident ----
    compute(1);

    // ---- epilogue: C/D layout col=lane&15, row=(lane>>4)*4+r ----
    #pragma unroll
    for (int m = 0; m < 4; ++m)
        #pragma unroll
        for (int nf = 0; nf < 4; ++nf)
            #pragma unroll
            for (int r = 0; r < 4; ++r) {
                const int row = wm * 64 + m * 16 + kgl * 4 + r;
                const int col = wn * 64 + nf * 16 + r15;
                gO[(size_t)row * HW + col] = acc[m][nf][r];
            }
}

extern "C" void kernel_launch(void* const* d_in, const int* in_sizes, int n_in,
                              void* d_out, int out_size, void* d_ws, size_t ws_size,
                              hipStream_t stream) {
    const float* images = (const float*)d_in[0];
    const float* atts   = (const float*)d_in[1];
    float*       out    = (float*)d_out;
    unsigned short* Wbf = (unsigned short*)d_ws;   // 32*512*512*2 = 16.8 MB

    softmax_rows<<<dim3(NB * CC / 4), dim3(256), 0, stream>>>(atts, Wbf);
    gemm_kernel<<<dim3(NB * (CC / BM) * (HW / BN)), dim3(256), 0, stream>>>(images, Wbf, out);
}

// Round 4
// 48.446 us; speedup vs baseline: 1.1497x; 1.0254x over previous
//
#include <hip/hip_runtime.h>
#include <stdint.h>

typedef __attribute__((ext_vector_type(4))) float  f32x4;
typedef __attribute__((ext_vector_type(8))) __bf16 bf16x8;

#define NB   32
#define CC   512
#define DD   512
#define HW   1024
#define BM   128
#define BN   128
#define BK   32

#define WAITV(N) asm volatile("s_waitcnt vmcnt(" #N ")" ::: "memory")
#define WAITL()  asm volatile("s_waitcnt lgkmcnt(0)" ::: "memory")
#define FENCE()  asm volatile("" ::: "memory")
#define BARR()   do { FENCE(); __builtin_amdgcn_s_barrier(); FENCE(); } while (0)

static __device__ __forceinline__ uint32_t f2bf(float x) {
    uint32_t u = __float_as_uint(x);
    return (u + 0x7FFFu + ((u >> 16) & 1u)) >> 16;   // RNE bf16
}

// ---------------- softmax over last dim of atts -> bf16 W in ws -------------
__global__ __launch_bounds__(256) void softmax_rows(
        const float* __restrict__ atts, unsigned short* __restrict__ W) {
    const int tid  = threadIdx.x;
    const int wid  = tid >> 6;
    const int lane = tid & 63;
    const int row  = blockIdx.x * 4 + wid;          // 0..16383
    const float* a = atts + (size_t)row * DD;

    float4 v0 = *(const float4*)(a + lane * 4);
    float4 v1 = *(const float4*)(a + 256 + lane * 4);
    float e[8] = {v0.x, v0.y, v0.z, v0.w, v1.x, v1.y, v1.z, v1.w};

    float m = e[0];
    #pragma unroll
    for (int j = 1; j < 8; ++j) m = fmaxf(m, e[j]);
    #pragma unroll
    for (int s = 1; s < 64; s <<= 1) m = fmaxf(m, __shfl_xor(m, s, 64));

    float sum = 0.f;
    #pragma unroll
    for (int j = 0; j < 8; ++j) { e[j] = __expf(e[j] - m); sum += e[j]; }
    #pragma unroll
    for (int s = 1; s < 64; s <<= 1) sum += __shfl_xor(sum, s, 64);
    const float inv = 1.0f / sum;

    uint32_t p[4];
    #pragma unroll
    for (int j = 0; j < 4; ++j)
        p[j] = f2bf(e[2*j] * inv) | (f2bf(e[2*j+1] * inv) << 16);

    unsigned short* wr = W + (size_t)row * DD;
    uint2 s0 = {p[0], p[1]};
    uint2 s1 = {p[2], p[3]};
    *(uint2*)(wr + lane * 4)       = s0;
    *(uint2*)(wr + 256 + lane * 4) = s1;
}

// ---------------- batched GEMM: out[n] = W[n] (512x512) x images[n] (512x1024)
// Deep counted-vmcnt pipeline:
//   B: 3 register sets, loaded 2 iterations ahead (load ks+3 at iter ks)
//   A: 2 LDS buffers via global_load_lds, staged 1 iteration ahead
//   lB: 3 LDS buffers (write one iter ahead of consume), ONE barrier/iter,
//   all global issues AFTER the barrier (no WAR races, max issue-to-wait gap)
__global__ __launch_bounds__(256) void gemm_kernel(
        const float* __restrict__ images, const unsigned short* __restrict__ W,
        float* __restrict__ out) {
    __shared__ unsigned short lA[2][BM * BK];       // 16 KB, src-preswizzled
    __shared__ unsigned short lB[3][4 * BN * 8];    // 24 KB, slot-swizzled

    // XCD-aware swizzle: all 32 tiles of batch n land on XCD n%8
    const int b  = blockIdx.x;       // 0..1023
    const int g  = b & 7;
    const int i  = b >> 3;
    const int n  = (i >> 5) * 8 + g; // batch 0..31
    const int tl = i & 31;
    const int mb = tl >> 3;          // 0..3
    const int nb = tl & 7;           // 0..7

    const float*          gI = images + (size_t)n * DD * HW + nb * BN;
    const unsigned short* gW = W + (size_t)n * CC * DD + (size_t)(mb * BM) * DD;
    float*                gO = out + (size_t)n * CC * HW + (size_t)(mb * BM) * HW + nb * BN;

    const int tid  = threadIdx.x;
    const int lane = tid & 63;
    const int wid  = tid >> 6;
    const int wm   = wid >> 1;
    const int wn   = wid & 1;
    const int bkg  = wid;            // B staging k-group = wave id
    const int bn   = lane * 2;
    const int r15  = lane & 15;
    const int kgl  = lane >> 4;

    // lB slot swizzle: s ^= (s>>3)&1 (16B granule)
    const int wfl = (lane >> 2) & 1;
    const int rfl = (r15 >> 3) & 1;
    const int ws0 = (bkg * BN + bn) ^ wfl;
    const int ws1 = (bkg * BN + bn + 1) ^ wfl;
    // lA read sub-slot swizzle (source is pre-swizzled to match)
    const int ksw = (kgl ^ (r15 & 3)) * 8;

    f32x4 acc[4][4] = {};
    float2 r0[8], r1[8], r2[8];      // three B register sets (2-iter lookahead)

    auto stage_a = [&](int buf, int ks) {
        #pragma unroll
        for (int p = 0; p < 2; ++p) {
            const int idx = p * 256 + tid;
            const int row = idx >> 2;
            const int s   = idx & 3;
            const int ss  = s ^ (row & 3);          // inverse-swizzled source
            const unsigned short* src = gW + (size_t)row * DD + ks * BK + ss * 8;
            __builtin_amdgcn_global_load_lds(
                (const __attribute__((address_space(1))) void*)src,
                (__attribute__((address_space(3))) void*)&lA[buf][idx * 8],
                16, 0, 0);
        }
    };
    auto load_b = [&](int ks, float2 (&dst)[8]) {
        const float* srcB = gI + (size_t)(ks * BK + bkg * 8) * HW + bn;
        #pragma unroll
        for (int j = 0; j < 8; ++j)
            dst[j] = *(const float2*)(srcB + (size_t)j * HW);
    };
    auto write_b = [&](int buf, float2 (&us)[8]) {
        bf16x8 wa, wb;
        #pragma unroll
        for (int j = 0; j < 8; ++j) {
            wa[j] = (__bf16)us[j].x; wb[j] = (__bf16)us[j].y;
        }
        *(bf16x8*)&lB[buf][ws0 * 8] = wa;
        *(bf16x8*)&lB[buf][ws1 * 8] = wb;
    };
    auto compute = [&](int bA, int bB) {
        bf16x8 af[4], bv[4];
        #pragma unroll
        for (int m = 0; m < 4; ++m)
            af[m] = *(const bf16x8*)&lA[bA][(wm * 64 + m * 16 + r15) * BK + ksw];
        #pragma unroll
        for (int nf = 0; nf < 4; ++nf) {
            const int s = (kgl * BN + wn * 64 + nf * 16 + r15) ^ rfl;
            bv[nf] = *(const bf16x8*)&lB[bB][s * 8];
        }
        #pragma unroll
        for (int m = 0; m < 4; ++m)
            #pragma unroll
            for (int nf = 0; nf < 4; ++nf)
                acc[m][nf] = __builtin_amdgcn_mfma_f32_16x16x32_bf16(
                    af[m], bv[nf], acc[m][nf], 0, 0, 0);
    };

    // ---- prologue: queue order (fenced) = [B0 8][A0 2][B1 8][B2 8] ----
    load_b(0, r0); FENCE();
    stage_a(0, 0); FENCE();
    load_b(1, r1); FENCE();
    load_b(2, r2);
    WAITV(18);                       // B0 done
    write_b(0, r0);

    // ---- steady iters 0..12: top queue = [B(ks+1) 8, A(ks) 2, B(ks+2) 8] ----
    #pragma unroll
    for (int ks = 0; ks <= 12; ++ks) {
        WAITV(8);                    // B(ks+1) and A(ks) complete
        float2 (&us)[8] = (ks % 3 == 0) ? r1 : (ks % 3 == 1) ? r2 : r0;
        write_b((ks + 1) % 3, us);   // regset (ks+1)%3 -> lB[(ks+1)%3]
        WAITL();
        BARR();                      // the ONLY barrier this iteration
        stage_a((ks + 1) & 1, ks + 1); FENCE();
        float2 (&ld)[8] = (ks % 3 == 0) ? r0 : (ks % 3 == 1) ? r1 : r2;
        load_b(ks + 3, ld);          // regset (ks+3)%3 == ks%3
        compute(ks & 1, ks % 3);
    }

    // ---- iter 13: top = [B14, A13, B15]; no more B loads ----
    WAITV(8);                        // B14, A13 done
    write_b(2, r2);
    WAITL(); BARR();
    stage_a(0, 14); FENCE();
    compute(1, 1);

    // ---- iter 14: top = [B15 8, A14 2] ----
    WAITV(0);                        // B15, A14 done
    write_b(0, r0);
    WAITL(); BARR();
    stage_a(1, 15); FENCE();
    compute(0, 2);

    // ---- iter 15 ----
    WAITV(0);                        // A15 done
    BARR();
    compute(1, 0);

    // ---- epilogue: C/D layout col=lane&15, row=(lane>>4)*4+r ----
    #pragma unroll
    for (int m = 0; m < 4; ++m)
        #pragma unroll
        for (int nf = 0; nf < 4; ++nf)
            #pragma unroll
            for (int r = 0; r < 4; ++r) {
                const int row = wm * 64 + m * 16 + kgl * 4 + r;
                const int col = wn * 64 + nf * 16 + r15;
                gO[(size_t)row * HW + col] = acc[m][nf][r];
            }
}

extern "C" void kernel_launch(void* const* d_in, const int* in_sizes, int n_in,
                              void* d_out, int out_size, void* d_ws, size_t ws_size,
                              hipStream_t stream) {
    const float* images = (const float*)d_in[0];
    const float* atts   = (const float*)d_in[1];
    float*       out    = (float*)d_out;
    unsigned short* Wbf = (unsigned short*)d_ws;   // 32*512*512*2 = 16.8 MB

    softmax_rows<<<dim3(NB * CC / 4), dim3(256), 0, stream>>>(atts, Wbf);
    gemm_kernel<<<dim3(NB * (CC / BM) * (HW / BN)), dim3(256), 0, stream>>>(images, Wbf, out);
}

// Round 5
// 45.733 us; speedup vs baseline: 1.2179x; 1.0593x over previous
//
#include <hip/hip_runtime.h>
#include <stdint.h>

typedef __attribute__((ext_vector_type(4))) float  f32x4;
typedef __attribute__((ext_vector_type(8))) __bf16 bf16x8;

#define NB   32
#define CC   512
#define DD   512
#define HW   1024
#define BM   256
#define BN   128
#define BK   32

#define WAITV(N) asm volatile("s_waitcnt vmcnt(" #N ")" ::: "memory")
#define WAITL()  asm volatile("s_waitcnt lgkmcnt(0)" ::: "memory")
#define FENCE()  asm volatile("" ::: "memory")
#define BARR()   do { FENCE(); __builtin_amdgcn_s_barrier(); FENCE(); } while (0)

static __device__ __forceinline__ uint32_t f2bf(float x) {
    uint32_t u = __float_as_uint(x);
    return (u + 0x7FFFu + ((u >> 16) & 1u)) >> 16;   // RNE bf16
}

// ---------------- softmax over last dim of atts -> bf16 W in ws -------------
__global__ __launch_bounds__(256) void softmax_rows(
        const float* __restrict__ atts, unsigned short* __restrict__ W) {
    const int tid  = threadIdx.x;
    const int wid  = tid >> 6;
    const int lane = tid & 63;
    const int row  = blockIdx.x * 4 + wid;          // 0..16383
    const float* a = atts + (size_t)row * DD;

    float4 v0 = *(const float4*)(a + lane * 4);
    float4 v1 = *(const float4*)(a + 256 + lane * 4);
    float e[8] = {v0.x, v0.y, v0.z, v0.w, v1.x, v1.y, v1.z, v1.w};

    float m = e[0];
    #pragma unroll
    for (int j = 1; j < 8; ++j) m = fmaxf(m, e[j]);
    #pragma unroll
    for (int s = 1; s < 64; s <<= 1) m = fmaxf(m, __shfl_xor(m, s, 64));

    float sum = 0.f;
    #pragma unroll
    for (int j = 0; j < 8; ++j) { e[j] = __expf(e[j] - m); sum += e[j]; }
    #pragma unroll
    for (int s = 1; s < 64; s <<= 1) sum += __shfl_xor(sum, s, 64);
    const float inv = 1.0f / sum;

    uint32_t p[4];
    #pragma unroll
    for (int j = 0; j < 4; ++j)
        p[j] = f2bf(e[2*j] * inv) | (f2bf(e[2*j+1] * inv) << 16);

    unsigned short* wr = W + (size_t)row * DD;
    uint2 q0 = {p[0], p[1]};
    uint2 q1 = {p[2], p[3]};
    *(uint2*)(wr + lane * 4)       = q0;
    *(uint2*)(wr + 256 + lane * 4) = q1;
}

// ---------------- batched GEMM: out[n] = W[n] (512x512) x images[n] (512x1024)
// BM=256 x BN=128 tile, 4 waves of 128x64 (acc[8][4]); counted-vmcnt pipeline:
//   body(ks): compute(ks) -> WAITV(8) -> write_b(ks+1) -> WAITL -> BARR
//             -> stage_a(ks+2) -> load_b(ks+3)
// A-safety is cross-wave correct: every wave drains its A(ks+1) gloads at the
// WAITV(8) BEFORE the barrier that precedes compute(ks+1).
__global__ __launch_bounds__(256, 2) void gemm_kernel(
        const float* __restrict__ images, const unsigned short* __restrict__ W,
        float* __restrict__ out) {
    __shared__ unsigned short lA[2][BM * BK];       // 2 x 16KB, src-preswizzled
    __shared__ unsigned short lB[2][4 * BN * 8];    // 2 x 8KB, slot-swizzled

    // XCD-aware swizzle: all 16 tiles of batch n land on XCD n%8
    const int b  = blockIdx.x;       // 0..511
    const int g  = b & 7;
    const int i  = b >> 3;           // 0..63
    const int n  = (i >> 4) * 8 + g; // batch 0..31
    const int tl = i & 15;
    const int mb = tl >> 3;          // 0..1
    const int nb = tl & 7;           // 0..7

    const float*          gI = images + (size_t)n * DD * HW + nb * BN;
    const unsigned short* gW = W + (size_t)n * CC * DD + (size_t)(mb * BM) * DD;
    float*                gO = out + (size_t)n * CC * HW + (size_t)(mb * BM) * HW + nb * BN;

    const int tid  = threadIdx.x;
    const int lane = tid & 63;
    const int wid  = tid >> 6;
    const int wm   = wid >> 1;       // 0..1 (row half, 128 rows)
    const int wn   = wid & 1;        // 0..1 (col half, 64 cols)
    const int bkg  = wid;            // B staging k-group = wave id
    const int bn   = lane * 2;
    const int r15  = lane & 15;
    const int kgl  = lane >> 4;

    // lB slot swizzle: s ^= (s>>3)&1 (16B granule)
    const int wfl = (lane >> 2) & 1;
    const int rfl = (r15 >> 3) & 1;
    const int ws0 = (bkg * BN + bn) ^ wfl;
    const int ws1 = (bkg * BN + bn + 1) ^ wfl;
    // lA k-slot swizzle (2 XOR terms -> 2-way/free bank pattern on af reads)
    const int sst = (kgl ^ (r15 & 3) ^ ((r15 >> 2) & 3)) * 8;

    f32x4 acc[8][4] = {};
    float2 s0[8], s1[8];             // two B register sets (2-iter flight)

    auto stage_a = [&](int buf, int ks) {
        #pragma unroll
        for (int p = 0; p < 4; ++p) {
            const int idx = p * 256 + tid;
            const int row = idx >> 2;
            const int s   = idx & 3;
            const int ss  = s ^ (row & 3) ^ ((row >> 2) & 3);   // inverse-swz src
            const unsigned short* src = gW + (size_t)row * DD + ks * BK + ss * 8;
            __builtin_amdgcn_global_load_lds(
                (const __attribute__((address_space(1))) void*)src,
                (__attribute__((address_space(3))) void*)&lA[buf][idx * 8],
                16, 0, 0);
        }
    };
    auto load_b = [&](int ks, float2 (&dst)[8]) {
        const float* srcB = gI + (size_t)(ks * BK + bkg * 8) * HW + bn;
        #pragma unroll
        for (int j = 0; j < 8; ++j)
            dst[j] = *(const float2*)(srcB + (size_t)j * HW);
    };
    auto write_b = [&](int buf, float2 (&us)[8]) {
        bf16x8 wa, wb;
        #pragma unroll
        for (int j = 0; j < 8; ++j) {
            wa[j] = (__bf16)us[j].x; wb[j] = (__bf16)us[j].y;
        }
        *(bf16x8*)&lB[buf][ws0 * 8] = wa;
        *(bf16x8*)&lB[buf][ws1 * 8] = wb;
    };
    auto compute = [&](int buf) {
        bf16x8 af[8], bv[4];
        #pragma unroll
        for (int m = 0; m < 8; ++m)
            af[m] = *(const bf16x8*)&lA[buf][(wm * 128 + m * 16 + r15) * BK + sst];
        #pragma unroll
        for (int nf = 0; nf < 4; ++nf) {
            const int s = (kgl * BN + wn * 64 + nf * 16 + r15) ^ rfl;
            bv[nf] = *(const bf16x8*)&lB[buf][s * 8];
        }
        #pragma unroll
        for (int m = 0; m < 8; ++m)
            #pragma unroll
            for (int nf = 0; nf < 4; ++nf)
                acc[m][nf] = __builtin_amdgcn_mfma_f32_16x16x32_bf16(
                    af[m], bv[nf], acc[m][nf], 0, 0, 0);
    };

    // ---- prologue: reach invariant Q(0) = [B1:8, A1:4, B2:8] ----
    load_b(0, s0); FENCE();          // [B0:8]
    stage_a(0, 0); FENCE();          // [B0, A0:4]
    load_b(1, s1); FENCE();          // [B0, A0, B1:8]
    WAITV(12);                       // B0 done
    write_b(0, s0);                  // tile0 -> lB[0]
    stage_a(1, 1); FENCE();          // [A0, B1, A1:4]
    load_b(2, s0); FENCE();          // [A0, B1, A1, B2:8] = 24
    WAITV(20);                       // A0 done (all waves, pre-barrier)
    WAITL();
    BARR();

    // ---- main loop ks = 0..12 ----
    // Q(ks) = [B(ks+1):8, A(ks+1):4, B(ks+2):8]; tiles t live in lA/lB[t&1]
    auto body = [&](int ks, float2 (&use)[8]) {
        compute(ks & 1);             // A/B safety from prev iter's WAITV+BARR
        WAITV(8);                    // B(ks+1) regs + A(ks+1) landed
        write_b((ks + 1) & 1, use);
        WAITL();
        BARR();
        stage_a(ks & 1, ks + 2); FENCE();
        load_b(ks + 3, use); FENCE();   // refill same set (consumed at ks+2)
    };
    #pragma unroll
    for (int ks = 0; ks <= 12; ++ks) {
        if (ks & 1) body(ks, s0);    // odd ks: use/refill s0
        else        body(ks, s1);    // even ks: use/refill s1
    }

    // ---- iter 13: Q = [B14:8, A14:4, B15:8]; no more B loads ----
    compute(1);
    WAITV(8);                        // B14, A14 done
    write_b(0, s0);
    WAITL(); BARR();
    stage_a(1, 15); FENCE();         // [B15:8, A15:4]

    // ---- iter 14 ----
    compute(0);
    WAITV(0);                        // B15, A15 done
    write_b(1, s1);
    WAITL(); BARR();

    // ---- iter 15 ----
    compute(1);

    // ---- epilogue: C/D layout col=lane&15, row=(lane>>4)*4+r ----
    #pragma unroll
    for (int m = 0; m < 8; ++m)
        #pragma unroll
        for (int nf = 0; nf < 4; ++nf)
            #pragma unroll
            for (int r = 0; r < 4; ++r) {
                const int row = wm * 128 + m * 16 + kgl * 4 + r;
                const int col = wn * 64 + nf * 16 + r15;
                gO[(size_t)row * HW + col] = acc[m][nf][r];
            }
}

extern "C" void kernel_launch(void* const* d_in, const int* in_sizes, int n_in,
                              void* d_out, int out_size, void* d_ws, size_t ws_size,
                              hipStream_t stream) {
    const float* images = (const float*)d_in[0];
    const float* atts   = (const float*)d_in[1];
    float*       out    = (float*)d_out;
    unsigned short* Wbf = (unsigned short*)d_ws;   // 32*512*512*2 = 16.8 MB

    softmax_rows<<<dim3(NB * CC / 4), dim3(256), 0, stream>>>(atts, Wbf);
    gemm_kernel<<<dim3(NB * (CC / BM) * (HW / BN)), dim3(256), 0, stream>>>(images, Wbf, out);
}